// Round 8
// baseline (452.891 us; speedup 1.0000x reference)
//
#include <hip/hip_runtime.h>
#include <hip/hip_fp16.h>

#define LEAKY_SLOPE 0.01f
#define LN_EPS 1e-6f
#define SUBS 8            // sub-slabs per bucket, one per XCD
#define CAP 352           // slots per (bucket, sub): mean ~256, +6 sigma
#define MAXE (SUBS*CAP)   // 2816 max edges per bucket
#define CSTRIDE 16        // ints per cursor counter: one counter per 64B line

typedef float  f4v __attribute__((ext_vector_type(4)));

__device__ __forceinline__ float head_sel(int h, float a, float b, float c, float d) {
    float lo = (h & 1) ? b : a;
    float hi = (h & 1) ? d : c;
    return (h & 2) ? hi : lo;
}

// payload: {lm0 f32, lm1 f32, (lm2 h | lm3 h<<16), (sender u16 | rloc<<16)}
__device__ __forceinline__ float unpack_lm(int h, int4 p) {
    unsigned pa = (unsigned)p.z;
    float lm2 = __half2float(__ushort_as_half((unsigned short)(pa & 0xFFFFu)));
    float lm3 = __half2float(__ushort_as_half((unsigned short)(pa >> 16)));
    return head_sel(h, __int_as_float(p.x), __int_as_float(p.y), lm2, lm3);
}

__device__ __forceinline__ int xcc_id() {
    // HW_REG_XCC_ID (id=20), offset 0, width 4  [measured: learn_hip m09]
    return (int)(__builtin_amdgcn_s_getreg(20 | (3 << 11)) & 7);
}

// ---------------------------------------------------------------------------
// K1: node projection, shuffle-free. Lane o holds W row o in 64 VGPRs.
// Wn stored FP16 (K4 gathers at half the bytes; table ~L2/L3-resident).
// Also zeroes cursor (fused memset).
// ---------------------------------------------------------------------------
__global__ __launch_bounds__(256) void node_proj_kernel(
    const float* __restrict__ nodes, const float* __restrict__ W,
    const float* __restrict__ a, __half* __restrict__ Wn16,
    float* __restrict__ s_s, float* __restrict__ s_r,
    float* __restrict__ lm_self, int* __restrict__ cursor,
    int ncursor, int N)
{
    int t = threadIdx.x;
    int ci = blockIdx.x * 256 + t;
    if (ci < ncursor) cursor[ci] = 0;

    int lane = t & 63;
    int wv = t >> 6;
    float w[64];
    const float4* W4 = (const float4*)W;
    #pragma unroll
    for (int i = 0; i < 16; i++) {
        float4 v = W4[lane * 16 + i];
        w[4*i] = v.x; w[4*i+1] = v.y; w[4*i+2] = v.z; w[4*i+3] = v.w;
    }
    int h = lane >> 4, f = lane & 15;
    float as_ = a[h * 48 + f];
    float ar_ = a[h * 48 + 16 + f];
    int n0 = blockIdx.x * 16 + wv * 4;
    #pragma unroll
    for (int k = 0; k < 4; k++) {
        int n = n0 + k;
        if (n >= N) break;
        const float4* row4 = (const float4*)(nodes + (size_t)n * 64);
        float acc = 0.f;
        #pragma unroll
        for (int c = 0; c < 16; c++) {
            float4 v = row4[c];   // same address across lanes -> broadcast
            acc += v.x * w[4*c] + v.y * w[4*c+1] + v.z * w[4*c+2] + v.w * w[4*c+3];
        }
        Wn16[(size_t)n * 64 + lane] = __float2half(acc);
        float ps = acc * as_;
        float pr = acc * ar_;
        #pragma unroll
        for (int off = 1; off < 16; off <<= 1) {
            ps += __shfl_xor(ps, off);
            pr += __shfl_xor(pr, off);
        }
        if (f == 0) {
            s_s[n * 4 + h] = ps;
            s_r[n * 4 + h] = pr;
            float v = ps + pr;
            lm_self[n * 4 + h] = v > 0.f ? v : LEAKY_SLOPE * v;
        }
    }
}

// ---------------------------------------------------------------------------
// K2: per-edge logits + bucket-append into XCD-private sub-slabs.
// Simple one-edge-per-thread form (R4/R5 chunked variants both slower).
// nt loads on read-once streams keep the edge stream out of L2.
// Payload 16B: {lm0 f32, lm1 f32, (lm2 h | lm3 h<<16), (sender u16 | rloc<<16)}
// ---------------------------------------------------------------------------
__global__ __launch_bounds__(256) void edge_bin_kernel(
    const float* __restrict__ edges, const int* __restrict__ receivers,
    const int* __restrict__ senders, const float* __restrict__ W_edge,
    const float* __restrict__ a, const float* __restrict__ s_s,
    const float* __restrict__ s_r, int* __restrict__ cursor,
    int4* __restrict__ slab, int E)
{
    __shared__ float be[4][16];   // be[h][i] = sum_f W_edge[h,f,i]*a_e[h,f]
    int t = threadIdx.x;
    int e = blockIdx.x * 256 + t;
    bool act = e < E;
    int r = 0, s = 0;
    if (act) {
        r = __builtin_nontemporal_load(receivers + e);
        s = __builtin_nontemporal_load(senders + e);
    }
    if (t < 64) {
        int h = t >> 4, i = t & 15;
        float sm = 0.f;
        #pragma unroll
        for (int f = 0; f < 16; f++)
            sm += W_edge[(h * 16 + f) * 16 + i] * a[h * 48 + 32 + f];
        be[h][i] = sm;
    }
    __syncthreads();
    if (!act) return;

    // reserve slot first: atomic latency overlaps the loads/compute below
    int b = r >> 6;
    int cidx = b * SUBS + xcc_id();
    int slot = __hip_atomic_fetch_add(&cursor[cidx * CSTRIDE], 1,
                                      __ATOMIC_RELAXED,
                                      __HIP_MEMORY_SCOPE_WORKGROUP);

    const f4v* ef = (const f4v*)(edges + (size_t)e * 16);
    f4v e0 = __builtin_nontemporal_load(ef);
    f4v e1 = __builtin_nontemporal_load(ef + 1);
    f4v e2 = __builtin_nontemporal_load(ef + 2);
    f4v e3 = __builtin_nontemporal_load(ef + 3);
    float4 ssv = ((const float4*)s_s)[s];
    float4 srv = ((const float4*)s_r)[r];
    float ev[16] = {e0[0], e0[1], e0[2], e0[3], e1[0], e1[1], e1[2], e1[3],
                    e2[0], e2[1], e2[2], e2[3], e3[0], e3[1], e3[2], e3[3]};
    float ssa[4] = {ssv.x, ssv.y, ssv.z, ssv.w};
    float sra[4] = {srv.x, srv.y, srv.z, srv.w};
    float lm[4];
    #pragma unroll
    for (int hh = 0; hh < 4; hh++) {
        float se = 0.f;
        #pragma unroll
        for (int i = 0; i < 16; i++) se += be[hh][i] * ev[i];
        float v = ssa[hh] + sra[hh] + se;
        lm[hh] = v > 0.f ? v : LEAKY_SLOPE * v;
    }
    if (slot < CAP) {
        unsigned packA = (unsigned)__half_as_ushort(__float2half(lm[2])) |
                         ((unsigned)__half_as_ushort(__float2half(lm[3])) << 16);
        unsigned packB = (unsigned)s | ((unsigned)(r & 63) << 16);
        slab[(size_t)cidx * CAP + slot] =
            make_int4(__float_as_int(lm[0]), __float_as_int(lm[1]),
                      (int)packA, (int)packB);
    }
}

// ---------------------------------------------------------------------------
// K34: fused sort+aggregate, one block per 64-node bucket.
// Pass 1: histogram local receivers from the slab's .w dwords.
// Pass 2: re-read slab (L2-hot) and place payloads SORTED directly into LDS.
// Phase D: wave wv aggregates nodes wv*16..wv*16+15; per edge, the payload
// is an LDS broadcast read (raw[off+k], same addr all lanes) and the Wn16
// row gather is 4-way unrolled (4 independent L2/L3 streams per wave).
// This differs from the R2 failed fusion exactly where it died: LDS (not
// serial global) payload broadcasts + 4x gather MLP + 12 waves/CU.
// Eliminates: K3's 26MB sorted write, K4's 26MB re-read, K4 staging, meta,
// one kernel launch.  LDS 45.8KB -> 3 blocks/CU.
// ---------------------------------------------------------------------------
__global__ __launch_bounds__(256) void sort_aggr_kernel(
    const __half* __restrict__ Wn16, const float* __restrict__ lm_self,
    const int* __restrict__ cursor, const int4* __restrict__ slab,
    const float* __restrict__ ln_scale, const float* __restrict__ ln_bias,
    float* __restrict__ out, int N)
{
    __shared__ int4 raw[MAXE];                 // 44 KB, sorted payloads
    __shared__ int cnt64[64];
    __shared__ int off64[64];
    __shared__ int cur64[64];

    int b = blockIdx.x;
    int t = threadIdx.x;

    if (t < 64) cnt64[t] = 0;
    __syncthreads();

    int c[SUBS];
    #pragma unroll
    for (int sub = 0; sub < SUBS; sub++)
        c[sub] = min(cursor[(b * SUBS + sub) * CSTRIDE], CAP);

    // pass 1: histogram local receivers (.w dword only; fetches the lines
    // pass 2 will hit in L2)
    #pragma unroll
    for (int sub = 0; sub < SUBS; sub++) {
        const int* srcW = (const int*)(slab + (size_t)(b * SUBS + sub) * CAP);
        for (int i = t; i < c[sub]; i += 256)
            atomicAdd(&cnt64[((unsigned)srcW[i * 4 + 3] >> 16) & 63], 1);
    }
    __syncthreads();

    // exclusive scan of cnt64 on wave 0
    if (t < 64) {
        int v = cnt64[t];
        int incl = v;
        #pragma unroll
        for (int off = 1; off < 64; off <<= 1) {
            int u = __shfl_up(incl, off);
            if (t >= off) incl += u;
        }
        off64[t] = incl - v;
        cur64[t] = incl - v;
    }
    __syncthreads();

    // pass 2: re-read full payloads (L2-hot) and place sorted into LDS
    #pragma unroll
    for (int sub = 0; sub < SUBS; sub++) {
        const int4* src = slab + (size_t)(b * SUBS + sub) * CAP;
        for (int i = t; i < c[sub]; i += 256) {
            int4 p = src[i];
            int rl = (int)(((unsigned)p.w >> 16) & 63u);
            int pos = atomicAdd(&cur64[rl], 1);
            raw[pos] = p;
        }
    }
    __syncthreads();

    // phase D: aggregation. wave wv owns nodes wv*16 .. wv*16+15.
    int lane = t & 63;
    int wv = t >> 6;
    int h = lane >> 4;

    for (int k = 0; k < 16; k++) {
        int nloc = wv * 16 + k;
        int n = b * 64 + nloc;
        if (n >= N) break;
        int cnt = cnt64[nloc];
        int off = off64[nloc];
        float a0 = 0.f, a1 = 0.f, a2 = 0.f, a3 = 0.f;
        float d0 = 0.f, d1 = 0.f, d2 = 0.f, d3 = 0.f;
        int j = 0;
        for (; j + 3 < cnt; j += 4) {
            int4 pA = raw[off + j];
            int4 pB = raw[off + j + 1];
            int4 pC = raw[off + j + 2];
            int4 pD = raw[off + j + 3];
            float wA = __expf(unpack_lm(h, pA));
            float wB = __expf(unpack_lm(h, pB));
            float wC = __expf(unpack_lm(h, pC));
            float wD = __expf(unpack_lm(h, pD));
            int sA = (int)((unsigned)pA.w & 0xFFFFu);
            int sB = (int)((unsigned)pB.w & 0xFFFFu);
            int sC = (int)((unsigned)pC.w & 0xFFFFu);
            int sD = (int)((unsigned)pD.w & 0xFFFFu);
            a0 += wA * __half2float(Wn16[(size_t)sA * 64 + lane]); d0 += wA;
            a1 += wB * __half2float(Wn16[(size_t)sB * 64 + lane]); d1 += wB;
            a2 += wC * __half2float(Wn16[(size_t)sC * 64 + lane]); d2 += wC;
            a3 += wD * __half2float(Wn16[(size_t)sD * 64 + lane]); d3 += wD;
        }
        for (; j < cnt; j++) {
            int4 pA = raw[off + j];
            float wA = __expf(unpack_lm(h, pA));
            int sA = (int)((unsigned)pA.w & 0xFFFFu);
            a0 += wA * __half2float(Wn16[(size_t)sA * 64 + lane]); d0 += wA;
        }
        float acc = (a0 + a1) + (a2 + a3);
        float den = (d0 + d1) + (d2 + d3);

        // self edge
        float4 ls = ((const float4*)lm_self)[n];
        float wself = __expf(head_sel(h, ls.x, ls.y, ls.z, ls.w));
        acc = (acc + wself * __half2float(Wn16[(size_t)n * 64 + lane])) / (den + wself);

        // ---- ELU + LayerNorm over the 64 features (= 64 lanes) ----
        float y = acc > 0.f ? acc : expm1f(acc);
        float sum = y;
        #pragma unroll
        for (int o2 = 1; o2 < 64; o2 <<= 1) sum += __shfl_xor(sum, o2);
        float mean = sum * 0.015625f;
        float d = y - mean;
        float vs = d * d;
        #pragma unroll
        for (int o2 = 1; o2 < 64; o2 <<= 1) vs += __shfl_xor(vs, o2);
        float var = vs * 0.015625f;
        float o = d * rsqrtf(var + LN_EPS) * ln_scale[lane] + ln_bias[lane];
        out[(size_t)n * 64 + lane] = o;
    }
}

// ---------------------------------------------------------------------------
extern "C" void kernel_launch(void* const* d_in, const int* in_sizes, int n_in,
                              void* d_out, int out_size, void* d_ws, size_t ws_size,
                              hipStream_t stream) {
    const float* nodes     = (const float*)d_in[0];
    const float* edges     = (const float*)d_in[1];
    const int*   receivers = (const int*)d_in[2];
    const int*   senders   = (const int*)d_in[3];
    const float* W         = (const float*)d_in[4];
    const float* W_edge    = (const float*)d_in[5];
    const float* a         = (const float*)d_in[6];
    const float* ln_scale  = (const float*)d_in[7];
    const float* ln_bias   = (const float*)d_in[8];
    float* out = (float*)d_out;

    int N = in_sizes[0] / 64;
    int E = in_sizes[2];
    int NB = (N + 63) / 64;   // buckets of 64 nodes
    int ncursor = NB * SUBS * CSTRIDE;

    char* ws = (char*)d_ws;
    size_t off = 0;
    auto alloc = [&](size_t bytes) -> void* {
        void* p = ws + off;
        off += (bytes + 15) & ~(size_t)15;
        return p;
    };
    __half* Wn16   = (__half*)alloc((size_t)N * 64 * 2);
    float* s_s     = (float*)alloc((size_t)N * 4 * 4);
    float* s_r     = (float*)alloc((size_t)N * 4 * 4);
    float* lm_self = (float*)alloc((size_t)N * 4 * 4);
    int*   cursor  = (int*)alloc((size_t)ncursor * 4);  // 64B/line-padded
    int4*  slab    = (int4*)alloc((size_t)NB * MAXE * 16);
    (void)ws_size; (void)n_in; (void)out_size;

    node_proj_kernel<<<(N + 15) / 16, 256, 0, stream>>>(
        nodes, W, a, Wn16, s_s, s_r, lm_self, cursor, ncursor, N);
    edge_bin_kernel<<<(E + 255) / 256, 256, 0, stream>>>(
        edges, receivers, senders, W_edge, a, s_s, s_r, cursor, slab, E);
    sort_aggr_kernel<<<NB, 256, 0, stream>>>(
        Wn16, lm_self, cursor, slab, ln_scale, ln_bias, out, N);
}

// Round 9
// 378.964 us; speedup vs baseline: 1.1951x; 1.1951x over previous
//
#include <hip/hip_runtime.h>
#include <hip/hip_fp16.h>

#define LEAKY_SLOPE 0.01f
#define LN_EPS 1e-6f
#define SUBS 8            // sub-slabs per bucket, one per XCD
#define CAP 352           // slots per (bucket, sub): mean ~256, +6 sigma
#define MAXE (SUBS*CAP)   // 2816 max edges per bucket
#define CSTRIDE 16        // ints per cursor counter: one counter per 64B line

typedef float  f4v __attribute__((ext_vector_type(4)));

__device__ __forceinline__ float head_sel(int h, float a, float b, float c, float d) {
    float lo = (h & 1) ? b : a;
    float hi = (h & 1) ? d : c;
    return (h & 2) ? hi : lo;
}

__device__ __forceinline__ int xcc_id() {
    // HW_REG_XCC_ID (id=20), offset 0, width 4  [measured: learn_hip m09]
    return (int)(__builtin_amdgcn_s_getreg(20 | (3 << 11)) & 7);
}

// ---------------------------------------------------------------------------
// K1: node projection, shuffle-free. Lane o holds W row o in 64 VGPRs.
// Wn stored FP16 (K4 gathers at half the bytes; table ~L2/L3-resident).
// Also zeroes cursor (fused memset).
// ---------------------------------------------------------------------------
__global__ __launch_bounds__(256) void node_proj_kernel(
    const float* __restrict__ nodes, const float* __restrict__ W,
    const float* __restrict__ a, __half* __restrict__ Wn16,
    float* __restrict__ s_s, float* __restrict__ s_r,
    float* __restrict__ lm_self, int* __restrict__ cursor,
    int ncursor, int N)
{
    int t = threadIdx.x;
    int ci = blockIdx.x * 256 + t;
    if (ci < ncursor) cursor[ci] = 0;

    int lane = t & 63;
    int wv = t >> 6;
    float w[64];
    const float4* W4 = (const float4*)W;
    #pragma unroll
    for (int i = 0; i < 16; i++) {
        float4 v = W4[lane * 16 + i];
        w[4*i] = v.x; w[4*i+1] = v.y; w[4*i+2] = v.z; w[4*i+3] = v.w;
    }
    int h = lane >> 4, f = lane & 15;
    float as_ = a[h * 48 + f];
    float ar_ = a[h * 48 + 16 + f];
    int n0 = blockIdx.x * 16 + wv * 4;
    #pragma unroll
    for (int k = 0; k < 4; k++) {
        int n = n0 + k;
        if (n >= N) break;
        const float4* row4 = (const float4*)(nodes + (size_t)n * 64);
        float acc = 0.f;
        #pragma unroll
        for (int c = 0; c < 16; c++) {
            float4 v = row4[c];   // same address across lanes -> broadcast
            acc += v.x * w[4*c] + v.y * w[4*c+1] + v.z * w[4*c+2] + v.w * w[4*c+3];
        }
        Wn16[(size_t)n * 64 + lane] = __float2half(acc);
        float ps = acc * as_;
        float pr = acc * ar_;
        #pragma unroll
        for (int off = 1; off < 16; off <<= 1) {
            ps += __shfl_xor(ps, off);
            pr += __shfl_xor(pr, off);
        }
        if (f == 0) {
            s_s[n * 4 + h] = ps;
            s_r[n * 4 + h] = pr;
            float v = ps + pr;
            lm_self[n * 4 + h] = v > 0.f ? v : LEAKY_SLOPE * v;
        }
    }
}

// ---------------------------------------------------------------------------
// K2: per-edge logits + bucket-append, TWO edges per thread (straightline
// dual issue). R8 analysis: at 72% occ each thread had ~6 loads in flight
// = 8.8 KB/CU, exactly at the Little's-law minimum for full HBM rate at
// 900cy latency — zero headroom. Two edges (256 apart, both halves wave-
// coalesced) double per-thread MLP; all loads for both edges issue before
// either compute. (R5's EPT=4 doesn't refute: its VGPR=32 shows the
// compiler serialized those loads.)
// Payload 16B: {lm0 f32, lm1 f32, (lm2 h | lm3 h<<16), (sender u16 | rloc<<16)}
// ---------------------------------------------------------------------------
__global__ __launch_bounds__(256) void edge_bin_kernel(
    const float* __restrict__ edges, const int* __restrict__ receivers,
    const int* __restrict__ senders, const float* __restrict__ W_edge,
    const float* __restrict__ a, const float* __restrict__ s_s,
    const float* __restrict__ s_r, int* __restrict__ cursor,
    int4* __restrict__ slab, int E)
{
    __shared__ float be[4][16];   // be[h][i] = sum_f W_edge[h,f,i]*a_e[h,f]
    int t = threadIdx.x;
    int eA = blockIdx.x * 512 + t;
    int eB = eA + 256;
    bool actA = eA < E, actB = eB < E;
    int rA = 0, sA = 0, rB = 0, sB = 0;
    if (actA) {
        rA = __builtin_nontemporal_load(receivers + eA);
        sA = __builtin_nontemporal_load(senders + eA);
    }
    if (actB) {
        rB = __builtin_nontemporal_load(receivers + eB);
        sB = __builtin_nontemporal_load(senders + eB);
    }
    if (t < 64) {
        int h = t >> 4, i = t & 15;
        float sm = 0.f;
        #pragma unroll
        for (int f = 0; f < 16; f++)
            sm += W_edge[(h * 16 + f) * 16 + i] * a[h * 48 + 32 + f];
        be[h][i] = sm;
    }
    __syncthreads();
    if (!actA) return;   // eB > eA, so !actA implies !actB

    int xcd = xcc_id();

    // reserve slots first: atomic latency overlaps the loads below
    int cidxA = (rA >> 6) * SUBS + xcd;
    int slotA = __hip_atomic_fetch_add(&cursor[cidxA * CSTRIDE], 1,
                                       __ATOMIC_RELAXED,
                                       __HIP_MEMORY_SCOPE_WORKGROUP);
    int cidxB = 0, slotB = 0;
    if (actB) {
        cidxB = (rB >> 6) * SUBS + xcd;
        slotB = __hip_atomic_fetch_add(&cursor[cidxB * CSTRIDE], 1,
                                       __ATOMIC_RELAXED,
                                       __HIP_MEMORY_SCOPE_WORKGROUP);
    }

    // issue ALL loads for both edges before any compute (12 independent)
    const f4v* efA = (const f4v*)(edges + (size_t)eA * 16);
    f4v a0 = __builtin_nontemporal_load(efA);
    f4v a1 = __builtin_nontemporal_load(efA + 1);
    f4v a2 = __builtin_nontemporal_load(efA + 2);
    f4v a3 = __builtin_nontemporal_load(efA + 3);
    float4 ssvA = ((const float4*)s_s)[sA];
    float4 srvA = ((const float4*)s_r)[rA];
    f4v b0, b1, b2, b3;
    float4 ssvB, srvB;
    if (actB) {
        const f4v* efB = (const f4v*)(edges + (size_t)eB * 16);
        b0 = __builtin_nontemporal_load(efB);
        b1 = __builtin_nontemporal_load(efB + 1);
        b2 = __builtin_nontemporal_load(efB + 2);
        b3 = __builtin_nontemporal_load(efB + 3);
        ssvB = ((const float4*)s_s)[sB];
        srvB = ((const float4*)s_r)[rB];
    }

    // edge A compute + store
    {
        float ev[16] = {a0[0], a0[1], a0[2], a0[3], a1[0], a1[1], a1[2], a1[3],
                        a2[0], a2[1], a2[2], a2[3], a3[0], a3[1], a3[2], a3[3]};
        float ssa[4] = {ssvA.x, ssvA.y, ssvA.z, ssvA.w};
        float sra[4] = {srvA.x, srvA.y, srvA.z, srvA.w};
        float lm[4];
        #pragma unroll
        for (int hh = 0; hh < 4; hh++) {
            float se = 0.f;
            #pragma unroll
            for (int i = 0; i < 16; i++) se += be[hh][i] * ev[i];
            float v = ssa[hh] + sra[hh] + se;
            lm[hh] = v > 0.f ? v : LEAKY_SLOPE * v;
        }
        if (slotA < CAP) {
            unsigned packA = (unsigned)__half_as_ushort(__float2half(lm[2])) |
                             ((unsigned)__half_as_ushort(__float2half(lm[3])) << 16);
            unsigned packB = (unsigned)sA | ((unsigned)(rA & 63) << 16);
            slab[(size_t)cidxA * CAP + slotA] =
                make_int4(__float_as_int(lm[0]), __float_as_int(lm[1]),
                          (int)packA, (int)packB);
        }
    }
    // edge B compute + store
    if (actB) {
        float ev[16] = {b0[0], b0[1], b0[2], b0[3], b1[0], b1[1], b1[2], b1[3],
                        b2[0], b2[1], b2[2], b2[3], b3[0], b3[1], b3[2], b3[3]};
        float ssa[4] = {ssvB.x, ssvB.y, ssvB.z, ssvB.w};
        float sra[4] = {srvB.x, srvB.y, srvB.z, srvB.w};
        float lm[4];
        #pragma unroll
        for (int hh = 0; hh < 4; hh++) {
            float se = 0.f;
            #pragma unroll
            for (int i = 0; i < 16; i++) se += be[hh][i] * ev[i];
            float v = ssa[hh] + sra[hh] + se;
            lm[hh] = v > 0.f ? v : LEAKY_SLOPE * v;
        }
        if (slotB < CAP) {
            unsigned packA = (unsigned)__half_as_ushort(__float2half(lm[2])) |
                             ((unsigned)__half_as_ushort(__float2half(lm[3])) << 16);
            unsigned packB = (unsigned)sB | ((unsigned)(rB & 63) << 16);
            slab[(size_t)cidxB * CAP + slotB] =
                make_int4(__float_as_int(lm[0]), __float_as_int(lm[1]),
                          (int)packA, (int)packB);
        }
    }
}

// ---------------------------------------------------------------------------
// K3: per-bucket in-LDS counting sort. Reads the bucket's sub-slabs, sorts by
// local receiver, writes back IN PLACE (coalesced) into the bucket's slab
// region, and emits per-node {beg, cnt} meta. (R7 perm-only variant and
// R2/R8 fusions all slower — this exact form is the measured best.)
// ---------------------------------------------------------------------------
__global__ __launch_bounds__(256) void bucket_sort_kernel(
    const int* __restrict__ cursor, int4* __restrict__ slab,
    int2* __restrict__ meta, int N)
{
    __shared__ int4 raw[MAXE];                 // 45 KB
    __shared__ unsigned short perm[MAXE];      // 5.5 KB
    __shared__ int cnt64[64];
    __shared__ int off64[64];
    __shared__ int cur64[64];

    int b = blockIdx.x;
    int t = threadIdx.x;
    int nn = min(64, N - b * 64);

    if (t < 64) cnt64[t] = 0;
    __syncthreads();

    int c[SUBS], basearr[SUBS];
    int tot = 0;
    #pragma unroll
    for (int sub = 0; sub < SUBS; sub++) {
        int cc = min(cursor[(b * SUBS + sub) * CSTRIDE], CAP);
        c[sub] = cc; basearr[sub] = tot; tot += cc;
    }

    // load slab -> LDS + histogram local receivers
    #pragma unroll
    for (int sub = 0; sub < SUBS; sub++) {
        int cc = c[sub], bs = basearr[sub];
        const int4* src = slab + (size_t)(b * SUBS + sub) * CAP;
        for (int i = t; i < cc; i += 256) {
            int4 p = src[i];
            raw[bs + i] = p;
            atomicAdd(&cnt64[((unsigned)p.w >> 16) & 63], 1);
        }
    }
    __syncthreads();

    // exclusive scan of cnt64 on wave 0
    if (t < 64) {
        int v = cnt64[t];
        int incl = v;
        #pragma unroll
        for (int off = 1; off < 64; off <<= 1) {
            int u = __shfl_up(incl, off);
            if (t >= off) incl += u;
        }
        off64[t] = incl - v;
        cur64[t] = incl - v;
    }
    __syncthreads();

    // build permutation: perm[sorted_pos] = raw index
    for (int i = t; i < tot; i += 256) {
        int rl = ((unsigned)raw[i].w >> 16) & 63;
        int pos = atomicAdd(&cur64[rl], 1);
        perm[pos] = (unsigned short)i;
    }
    __syncthreads();

    // coalesced write-back, in place (whole bucket already in LDS)
    int4* dst = slab + (size_t)b * MAXE;
    for (int pos = t; pos < tot; pos += 256)
        dst[pos] = raw[perm[pos]];

    if (t < nn)
        meta[b * 64 + t] = make_int2(b * MAXE + off64[t], cnt64[t]);
}

// ---------------------------------------------------------------------------
// K4: single-pass per-node softmax + aggregation + ELU + LN.
// One wave per node, lane = h*16+f owns one output feature. LDS-staged
// chunks, no barriers (wave-private LDS regions). Wn gathers fp16.
// ---------------------------------------------------------------------------
__global__ __launch_bounds__(256) void node_aggr_kernel(
    const __half* __restrict__ Wn16, const float* __restrict__ lm_self,
    const int2* __restrict__ meta, const int4* __restrict__ sorted,
    const float* __restrict__ ln_scale, const float* __restrict__ ln_bias,
    float* __restrict__ out, int N)
{
    __shared__ float lds_w[4][64][4];
    __shared__ int   lds_s[4][64];
    int t = threadIdx.x;
    int lane = t & 63;
    int wv = t >> 6;
    int n = blockIdx.x * 4 + wv;
    if (n >= N) return;
    int2 mt = meta[n];
    int beg = mt.x, cntn = mt.y;
    int h = lane >> 4;

    float acc = 0.f, acc2 = 0.f;
    float p0 = 0.f, p1 = 0.f, p2 = 0.f, p3 = 0.f;  // partial softmax denoms

    for (int base = 0; base < cntn; base += 64) {
        int j = base + lane;
        float w0 = 0.f, w1 = 0.f, w2 = 0.f, w3 = 0.f;
        int sv = 0;
        if (j < cntn) {
            int4 pl = sorted[beg + j];
            w0 = __expf(__int_as_float(pl.x));
            w1 = __expf(__int_as_float(pl.y));
            unsigned pa = (unsigned)pl.z;
            w2 = __expf(__half2float(__ushort_as_half((unsigned short)(pa & 0xFFFFu))));
            w3 = __expf(__half2float(__ushort_as_half((unsigned short)(pa >> 16))));
            sv = (int)((unsigned)pl.w & 0xFFFFu);
        }
        p0 += w0; p1 += w1; p2 += w2; p3 += w3;
        lds_s[wv][lane] = sv;
        *(float4*)&lds_w[wv][lane][0] = make_float4(w0, w1, w2, w3);
        int cnt = min(64, cntn - base);
        int k = 0;
        for (; k + 1 < cnt; k += 2) {
            int   sk0 = lds_s[wv][k];
            int   sk1 = lds_s[wv][k + 1];
            float a0  = lds_w[wv][k][h];
            float a1  = lds_w[wv][k + 1][h];
            acc  += a0 * __half2float(Wn16[(size_t)sk0 * 64 + lane]);
            acc2 += a1 * __half2float(Wn16[(size_t)sk1 * 64 + lane]);
        }
        if (k < cnt)
            acc += lds_w[wv][k][h] * __half2float(Wn16[(size_t)lds_s[wv][k] * 64 + lane]);
    }
    acc += acc2;

    // reduce softmax denominators across the wave
    #pragma unroll
    for (int off = 1; off < 64; off <<= 1) {
        p0 += __shfl_xor(p0, off);
        p1 += __shfl_xor(p1, off);
        p2 += __shfl_xor(p2, off);
        p3 += __shfl_xor(p3, off);
    }
    // self edge
    float4 ls = ((const float4*)lm_self)[n];
    float ws0 = __expf(ls.x), ws1 = __expf(ls.y);
    float ws2 = __expf(ls.z), ws3 = __expf(ls.w);
    float totd  = head_sel(h, p0 + ws0, p1 + ws1, p2 + ws2, p3 + ws3);
    float wself = head_sel(h, ws0, ws1, ws2, ws3);
    acc = (acc + wself * __half2float(Wn16[(size_t)n * 64 + lane])) / totd;

    // ---- ELU + LayerNorm over the 64 features (= 64 lanes) ----
    float y = acc > 0.f ? acc : expm1f(acc);
    float sum = y;
    #pragma unroll
    for (int off = 1; off < 64; off <<= 1) sum += __shfl_xor(sum, off);
    float mean = sum * 0.015625f;
    float d = y - mean;
    float vs = d * d;
    #pragma unroll
    for (int off = 1; off < 64; off <<= 1) vs += __shfl_xor(vs, off);
    float var = vs * 0.015625f;
    float o = d * rsqrtf(var + LN_EPS) * ln_scale[lane] + ln_bias[lane];
    out[(size_t)n * 64 + lane] = o;
}

// ---------------------------------------------------------------------------
extern "C" void kernel_launch(void* const* d_in, const int* in_sizes, int n_in,
                              void* d_out, int out_size, void* d_ws, size_t ws_size,
                              hipStream_t stream) {
    const float* nodes     = (const float*)d_in[0];
    const float* edges     = (const float*)d_in[1];
    const int*   receivers = (const int*)d_in[2];
    const int*   senders   = (const int*)d_in[3];
    const float* W         = (const float*)d_in[4];
    const float* W_edge    = (const float*)d_in[5];
    const float* a         = (const float*)d_in[6];
    const float* ln_scale  = (const float*)d_in[7];
    const float* ln_bias   = (const float*)d_in[8];
    float* out = (float*)d_out;

    int N = in_sizes[0] / 64;
    int E = in_sizes[2];
    int NB = (N + 63) / 64;   // buckets of 64 nodes
    int ncursor = NB * SUBS * CSTRIDE;

    char* ws = (char*)d_ws;
    size_t off = 0;
    auto alloc = [&](size_t bytes) -> void* {
        void* p = ws + off;
        off += (bytes + 15) & ~(size_t)15;
        return p;
    };
    __half* Wn16   = (__half*)alloc((size_t)N * 64 * 2);
    float* s_s     = (float*)alloc((size_t)N * 4 * 4);
    float* s_r     = (float*)alloc((size_t)N * 4 * 4);
    float* lm_self = (float*)alloc((size_t)N * 4 * 4);
    int*   cursor  = (int*)alloc((size_t)ncursor * 4);  // 64B/line-padded
    int2*  meta    = (int2*)alloc((size_t)N * 8);
    int4*  slab    = (int4*)alloc((size_t)NB * MAXE * 16);
    (void)ws_size; (void)n_in; (void)out_size;

    node_proj_kernel<<<(N + 15) / 16, 256, 0, stream>>>(
        nodes, W, a, Wn16, s_s, s_r, lm_self, cursor, ncursor, N);
    edge_bin_kernel<<<(E + 511) / 512, 256, 0, stream>>>(
        edges, receivers, senders, W_edge, a, s_s, s_r, cursor, slab, E);
    bucket_sort_kernel<<<NB, 256, 0, stream>>>(cursor, slab, meta, N);
    node_aggr_kernel<<<(N + 3) / 4, 256, 0, stream>>>(
        Wn16, lm_self, meta, slab, ln_scale, ln_bias, out, N);
}

// Round 10
// 368.393 us; speedup vs baseline: 1.2294x; 1.0287x over previous
//
#include <hip/hip_runtime.h>
#include <hip/hip_fp16.h>

#define LEAKY_SLOPE 0.01f
#define LN_EPS 1e-6f
#define SUBS 8            // sub-slabs per bucket, one per XCD
#define CAP 352           // slots per (bucket, sub): mean ~256, +6 sigma
#define MAXE (SUBS*CAP)   // 2816 max edges per bucket
#define CSTRIDE 16        // ints per cursor counter: one counter per 64B line

__device__ __forceinline__ float head_sel(int h, float a, float b, float c, float d) {
    float lo = (h & 1) ? b : a;
    float hi = (h & 1) ? d : c;
    return (h & 2) ? hi : lo;
}

__device__ __forceinline__ int xcc_id() {
    // HW_REG_XCC_ID (id=20), offset 0, width 4  [measured: learn_hip m09]
    return (int)(__builtin_amdgcn_s_getreg(20 | (3 << 11)) & 7);
}

// ---------------------------------------------------------------------------
// K1: node projection, shuffle-free. Lane o holds W row o in 64 VGPRs
// (Wn[n][o] = dot(nodes[n,:], W[o,:])). Node row is read by all 64 lanes at
// the SAME address (hardware broadcast). Wn is stored in FP16: its only
// consumer is K4's weighted sum (fp32 accum); fp16 halves K4's gather bytes
// and shrinks the table to 6.4MB (~L2/L3-resident). s_s/s_r/lm_self stay
// fp32 (computed from the fp32 accumulator). Also zeroes cursor (fused
// memset; K2 runs after K1 in stream order).
// ---------------------------------------------------------------------------
__global__ __launch_bounds__(256) void node_proj_kernel(
    const float* __restrict__ nodes, const float* __restrict__ W,
    const float* __restrict__ a, __half* __restrict__ Wn16,
    float* __restrict__ s_s, float* __restrict__ s_r,
    float* __restrict__ lm_self, int* __restrict__ cursor,
    int ncursor, int N)
{
    int t = threadIdx.x;
    // fused cursor clear (grid*256 >> ncursor)
    int ci = blockIdx.x * 256 + t;
    if (ci < ncursor) cursor[ci] = 0;

    int lane = t & 63;
    int wv = t >> 6;
    // lane-private W row: w[i] = W[lane*64 + i]
    float w[64];
    const float4* W4 = (const float4*)W;
    #pragma unroll
    for (int i = 0; i < 16; i++) {
        float4 v = W4[lane * 16 + i];
        w[4*i] = v.x; w[4*i+1] = v.y; w[4*i+2] = v.z; w[4*i+3] = v.w;
    }
    int h = lane >> 4, f = lane & 15;
    float as_ = a[h * 48 + f];
    float ar_ = a[h * 48 + 16 + f];
    int n0 = blockIdx.x * 16 + wv * 4;
    #pragma unroll
    for (int k = 0; k < 4; k++) {
        int n = n0 + k;
        if (n >= N) break;
        const float4* row4 = (const float4*)(nodes + (size_t)n * 64);
        float acc = 0.f;
        #pragma unroll
        for (int c = 0; c < 16; c++) {
            float4 v = row4[c];   // same address across lanes -> broadcast
            acc += v.x * w[4*c] + v.y * w[4*c+1] + v.z * w[4*c+2] + v.w * w[4*c+3];
        }
        Wn16[(size_t)n * 64 + lane] = __float2half(acc);
        float ps = acc * as_;
        float pr = acc * ar_;
        #pragma unroll
        for (int off = 1; off < 16; off <<= 1) {
            ps += __shfl_xor(ps, off);
            pr += __shfl_xor(pr, off);
        }
        if (f == 0) {
            s_s[n * 4 + h] = ps;
            s_r[n * 4 + h] = pr;
            float v = ps + pr;
            lm_self[n * 4 + h] = v > 0.f ? v : LEAKY_SLOPE * v;
        }
    }
}

// ---------------------------------------------------------------------------
// K2: per-edge logits + bucket-append into XCD-private sub-slabs.
// bucket = receiver >> 6. Cursor counters: one per 64B line (CSTRIDE).
// Counters are XCD-private (cidx includes xcc_id) -> workgroup-scope atomic.
// Atomic issued EARLY so its latency overlaps the feature loads + lm compute.
// STRUCTURAL FLOOR (~100us), established over 6 falsified theories:
// atomic scope (null), chunked store density x2 (negative), 1024t occupancy
// (null), nt loads (null), 2-edge MLP (null). 1.6M random 16B scatter
// granules run at ~1.5-1.6 TB/s effective on MI355X; byte count is within
// 10% of the algorithm's ideal. Do not re-mine without a new data flow.
// Payload 16B: {lm0 f32, lm1 f32, (lm2 h | lm3 h<<16), (sender u16 | rloc<<16)}
// ---------------------------------------------------------------------------
__global__ __launch_bounds__(256) void edge_bin_kernel(
    const float* __restrict__ edges, const int* __restrict__ receivers,
    const int* __restrict__ senders, const float* __restrict__ W_edge,
    const float* __restrict__ a, const float* __restrict__ s_s,
    const float* __restrict__ s_r, int* __restrict__ cursor,
    int4* __restrict__ slab, int E)
{
    __shared__ float be[4][16];   // be[h][i] = sum_f W_edge[h,f,i]*a_e[h,f]
    int t = threadIdx.x;
    int e = blockIdx.x * 256 + t;
    bool act = e < E;
    int r = 0, s = 0;
    if (act) { r = receivers[e]; s = senders[e]; }   // issue before barrier
    if (t < 64) {
        int h = t >> 4, i = t & 15;
        float sm = 0.f;
        #pragma unroll
        for (int f = 0; f < 16; f++)
            sm += W_edge[(h * 16 + f) * 16 + i] * a[h * 48 + 32 + f];
        be[h][i] = sm;
    }
    __syncthreads();
    if (!act) return;

    // reserve slot first: atomic latency overlaps the loads/compute below
    int b = r >> 6;
    int cidx = b * SUBS + xcc_id();
    int slot = __hip_atomic_fetch_add(&cursor[cidx * CSTRIDE], 1,
                                      __ATOMIC_RELAXED,
                                      __HIP_MEMORY_SCOPE_WORKGROUP);

    const float4* ef = (const float4*)(edges + (size_t)e * 16);
    float4 e0 = ef[0], e1 = ef[1], e2 = ef[2], e3 = ef[3];
    float4 ssv = ((const float4*)s_s)[s];
    float4 srv = ((const float4*)s_r)[r];
    float ev[16] = {e0.x, e0.y, e0.z, e0.w, e1.x, e1.y, e1.z, e1.w,
                    e2.x, e2.y, e2.z, e2.w, e3.x, e3.y, e3.z, e3.w};
    float ssa[4] = {ssv.x, ssv.y, ssv.z, ssv.w};
    float sra[4] = {srv.x, srv.y, srv.z, srv.w};
    float lm[4];
    #pragma unroll
    for (int hh = 0; hh < 4; hh++) {
        float se = 0.f;
        #pragma unroll
        for (int i = 0; i < 16; i++) se += be[hh][i] * ev[i];
        float v = ssa[hh] + sra[hh] + se;
        lm[hh] = v > 0.f ? v : LEAKY_SLOPE * v;
    }
    if (slot < CAP) {
        unsigned packA = (unsigned)__half_as_ushort(__float2half(lm[2])) |
                         ((unsigned)__half_as_ushort(__float2half(lm[3])) << 16);
        unsigned packB = (unsigned)s | ((unsigned)(r & 63) << 16);
        slab[(size_t)cidx * CAP + slot] =
            make_int4(__float_as_int(lm[0]), __float_as_int(lm[1]),
                      (int)packA, (int)packB);
    }
}

// ---------------------------------------------------------------------------
// K3: per-bucket in-LDS counting sort. Reads the bucket's sub-slabs, sorts by
// local receiver, writes back IN PLACE (coalesced) into the bucket's slab
// region, and emits per-node {beg, cnt} meta. Measured best of its family:
// perm-only variant (R7, +16us net) and both K3+K4 fusions (R2 +50, R8 +55)
// regressed — the coalesced payload round-trip is cheaper than any
// random-access scheme that avoids it.
// ---------------------------------------------------------------------------
__global__ __launch_bounds__(256) void bucket_sort_kernel(
    const int* __restrict__ cursor, int4* __restrict__ slab,
    int2* __restrict__ meta, int N)
{
    __shared__ int4 raw[MAXE];                 // 45 KB
    __shared__ unsigned short perm[MAXE];      // 5.5 KB
    __shared__ int cnt64[64];
    __shared__ int off64[64];
    __shared__ int cur64[64];

    int b = blockIdx.x;
    int t = threadIdx.x;
    int nn = min(64, N - b * 64);

    if (t < 64) cnt64[t] = 0;
    __syncthreads();

    int c[SUBS], basearr[SUBS];
    int tot = 0;
    #pragma unroll
    for (int sub = 0; sub < SUBS; sub++) {
        int cc = min(cursor[(b * SUBS + sub) * CSTRIDE], CAP);
        c[sub] = cc; basearr[sub] = tot; tot += cc;
    }

    // load slab -> LDS + histogram local receivers
    #pragma unroll
    for (int sub = 0; sub < SUBS; sub++) {
        int cc = c[sub], bs = basearr[sub];
        const int4* src = slab + (size_t)(b * SUBS + sub) * CAP;
        for (int i = t; i < cc; i += 256) {
            int4 p = src[i];
            raw[bs + i] = p;
            atomicAdd(&cnt64[((unsigned)p.w >> 16) & 63], 1);
        }
    }
    __syncthreads();

    // exclusive scan of cnt64 on wave 0
    if (t < 64) {
        int v = cnt64[t];
        int incl = v;
        #pragma unroll
        for (int off = 1; off < 64; off <<= 1) {
            int u = __shfl_up(incl, off);
            if (t >= off) incl += u;
        }
        off64[t] = incl - v;
        cur64[t] = incl - v;
    }
    __syncthreads();

    // build permutation: perm[sorted_pos] = raw index
    for (int i = t; i < tot; i += 256) {
        int rl = ((unsigned)raw[i].w >> 16) & 63;
        int pos = atomicAdd(&cur64[rl], 1);
        perm[pos] = (unsigned short)i;
    }
    __syncthreads();

    // coalesced write-back, in place (whole bucket already in LDS)
    int4* dst = slab + (size_t)b * MAXE;
    for (int pos = t; pos < tot; pos += 256)
        dst[pos] = raw[perm[pos]];

    if (t < nn)
        meta[b * 64 + t] = make_int2(b * MAXE + off64[t], cnt64[t]);
}

// ---------------------------------------------------------------------------
// K4: single-pass per-node softmax (no max-shift) + aggregation + ELU + LN.
// One wave per node, lane = h*16+f owns one output feature. LDS-staged
// chunks, no barriers (wave-private LDS regions). Wn gathers are fp16:
// halves the 410MB row-gather stream; 6.4MB table ~cache-resident.
// ---------------------------------------------------------------------------
__global__ __launch_bounds__(256) void node_aggr_kernel(
    const __half* __restrict__ Wn16, const float* __restrict__ lm_self,
    const int2* __restrict__ meta, const int4* __restrict__ sorted,
    const float* __restrict__ ln_scale, const float* __restrict__ ln_bias,
    float* __restrict__ out, int N)
{
    __shared__ float lds_w[4][64][4];
    __shared__ int   lds_s[4][64];
    int t = threadIdx.x;
    int lane = t & 63;
    int wv = t >> 6;
    int n = blockIdx.x * 4 + wv;
    if (n >= N) return;
    int2 mt = meta[n];
    int beg = mt.x, cntn = mt.y;
    int h = lane >> 4;

    float acc = 0.f, acc2 = 0.f;
    float p0 = 0.f, p1 = 0.f, p2 = 0.f, p3 = 0.f;  // partial softmax denoms

    for (int base = 0; base < cntn; base += 64) {
        int j = base + lane;
        float w0 = 0.f, w1 = 0.f, w2 = 0.f, w3 = 0.f;
        int sv = 0;
        if (j < cntn) {
            int4 pl = sorted[beg + j];
            w0 = __expf(__int_as_float(pl.x));
            w1 = __expf(__int_as_float(pl.y));
            unsigned pa = (unsigned)pl.z;
            w2 = __expf(__half2float(__ushort_as_half((unsigned short)(pa & 0xFFFFu))));
            w3 = __expf(__half2float(__ushort_as_half((unsigned short)(pa >> 16))));
            sv = (int)((unsigned)pl.w & 0xFFFFu);
        }
        p0 += w0; p1 += w1; p2 += w2; p3 += w3;
        lds_s[wv][lane] = sv;
        *(float4*)&lds_w[wv][lane][0] = make_float4(w0, w1, w2, w3);
        int cnt = min(64, cntn - base);
        int k = 0;
        for (; k + 1 < cnt; k += 2) {
            int   sk0 = lds_s[wv][k];
            int   sk1 = lds_s[wv][k + 1];
            float a0  = lds_w[wv][k][h];
            float a1  = lds_w[wv][k + 1][h];
            acc  += a0 * __half2float(Wn16[(size_t)sk0 * 64 + lane]);
            acc2 += a1 * __half2float(Wn16[(size_t)sk1 * 64 + lane]);
        }
        if (k < cnt)
            acc += lds_w[wv][k][h] * __half2float(Wn16[(size_t)lds_s[wv][k] * 64 + lane]);
    }
    acc += acc2;

    // reduce softmax denominators across the wave
    #pragma unroll
    for (int off = 1; off < 64; off <<= 1) {
        p0 += __shfl_xor(p0, off);
        p1 += __shfl_xor(p1, off);
        p2 += __shfl_xor(p2, off);
        p3 += __shfl_xor(p3, off);
    }
    // self edge
    float4 ls = ((const float4*)lm_self)[n];
    float ws0 = __expf(ls.x), ws1 = __expf(ls.y);
    float ws2 = __expf(ls.z), ws3 = __expf(ls.w);
    float totd  = head_sel(h, p0 + ws0, p1 + ws1, p2 + ws2, p3 + ws3);
    float wself = head_sel(h, ws0, ws1, ws2, ws3);
    acc = (acc + wself * __half2float(Wn16[(size_t)n * 64 + lane])) / totd;

    // ---- ELU + LayerNorm over the 64 features (= 64 lanes) ----
    float y = acc > 0.f ? acc : expm1f(acc);
    float sum = y;
    #pragma unroll
    for (int off = 1; off < 64; off <<= 1) sum += __shfl_xor(sum, off);
    float mean = sum * 0.015625f;
    float d = y - mean;
    float vs = d * d;
    #pragma unroll
    for (int off = 1; off < 64; off <<= 1) vs += __shfl_xor(vs, off);
    float var = vs * 0.015625f;
    float o = d * rsqrtf(var + LN_EPS) * ln_scale[lane] + ln_bias[lane];
    out[(size_t)n * 64 + lane] = o;
}

// ---------------------------------------------------------------------------
extern "C" void kernel_launch(void* const* d_in, const int* in_sizes, int n_in,
                              void* d_out, int out_size, void* d_ws, size_t ws_size,
                              hipStream_t stream) {
    const float* nodes     = (const float*)d_in[0];
    const float* edges     = (const float*)d_in[1];
    const int*   receivers = (const int*)d_in[2];
    const int*   senders   = (const int*)d_in[3];
    const float* W         = (const float*)d_in[4];
    const float* W_edge    = (const float*)d_in[5];
    const float* a         = (const float*)d_in[6];
    const float* ln_scale  = (const float*)d_in[7];
    const float* ln_bias   = (const float*)d_in[8];
    float* out = (float*)d_out;

    int N = in_sizes[0] / 64;
    int E = in_sizes[2];
    int NB = (N + 63) / 64;   // buckets of 64 nodes
    int ncursor = NB * SUBS * CSTRIDE;

    char* ws = (char*)d_ws;
    size_t off = 0;
    auto alloc = [&](size_t bytes) -> void* {
        void* p = ws + off;
        off += (bytes + 15) & ~(size_t)15;
        return p;
    };
    __half* Wn16   = (__half*)alloc((size_t)N * 64 * 2);
    float* s_s     = (float*)alloc((size_t)N * 4 * 4);
    float* s_r     = (float*)alloc((size_t)N * 4 * 4);
    float* lm_self = (float*)alloc((size_t)N * 4 * 4);
    int*   cursor  = (int*)alloc((size_t)ncursor * 4);  // 64B/line-padded
    int2*  meta    = (int2*)alloc((size_t)N * 8);
    int4*  slab    = (int4*)alloc((size_t)NB * MAXE * 16);
    (void)ws_size; (void)n_in; (void)out_size;

    node_proj_kernel<<<(N + 15) / 16, 256, 0, stream>>>(
        nodes, W, a, Wn16, s_s, s_r, lm_self, cursor, ncursor, N);
    edge_bin_kernel<<<(E + 255) / 256, 256, 0, stream>>>(
        edges, receivers, senders, W_edge, a, s_s, s_r, cursor, slab, E);
    bucket_sort_kernel<<<NB, 256, 0, stream>>>(cursor, slab, meta, N);
    node_aggr_kernel<<<(N + 3) / 4, 256, 0, stream>>>(
        Wn16, lm_self, meta, slab, ln_scale, ln_bias, out, N);
}